// Round 6
// baseline (1614.799 us; speedup 1.0000x reference)
//
#include <hip/hip_runtime.h>
#include <hip/hip_fp16.h>

typedef int      v4i __attribute__((ext_vector_type(4)));
typedef int      v2i __attribute__((ext_vector_type(2)));
typedef float    v4f __attribute__((ext_vector_type(4)));
typedef _Float16 v8h __attribute__((ext_vector_type(8)));
typedef _Float16 v4h __attribute__((ext_vector_type(4)));

#define MDIM 8192
#define NDIM 4096
#define KDIM 4096
#define RDIM 64
#define KW   (KDIM / 2)
#define NHALF (KDIM / 64)        // 64 K-halves of 64 int8

typedef const __attribute__((address_space(1))) char* gas_ptr;
typedef __attribute__((address_space(3))) char*       las_ptr;

__device__ __forceinline__ void unpack_w(v4i w, int& lo8, int& hi8) {
    unsigned p01 = __builtin_amdgcn_perm((unsigned)w.y, (unsigned)w.x, 0x0C0C0400u);
    unsigned p23 = __builtin_amdgcn_perm((unsigned)w.w, (unsigned)w.z, 0x0C0C0400u);
    unsigned b4  = __builtin_amdgcn_perm(p23, p01, 0x05040100u);
    unsigned lo = b4 & 0x0F0F0F0Fu;
    unsigned hi = (b4 >> 4) & 0x0F0F0F0Fu;
    lo8 = (int)(((lo ^ 0x08080808u) + 0x78787878u) ^ 0x80808080u);
    hi8 = (int)(((hi ^ 0x08080808u) + 0x78787878u) ^ 0x80808080u);
}

// ---------------- kernel 1: repack packed-int32 nibbles -> dense int8 -------
__global__ __launch_bounds__(256)
void repack_int4(const int* __restrict__ xq, const int* __restrict__ wq,
                 char* __restrict__ x8, char* __restrict__ w8)
{
    const size_t XCH = (size_t)MDIM * KW / 4;
    const size_t TCH = XCH + (size_t)NDIM * KW / 4;
    size_t stride = (size_t)gridDim.x * blockDim.x;
    for (size_t i = (size_t)blockIdx.x * blockDim.x + threadIdx.x; i < TCH; i += stride) {
        const int* src;
        char* dst;
        if (i < XCH) { src = xq + i * 4; dst = x8 + i * 8; }
        else { size_t j = i - XCH; src = wq + j * 4; dst = w8 + j * 8; }
        v4i w = *(const v4i*)src;
        int lo8, hi8;
        unpack_w(w, lo8, hi8);
        *(v2i*)dst = (v2i){lo8, hi8};
    }
}

// ---------------- kernel 2: 256x256 int8 GEMM, 2-deep LDS, 2 blocks/CU ------
// 64 KiB tile LDS (+3 KiB scales) -> 2 resident blocks/CU; the two blocks'
// barrier groups anti-phase and hide each other's ds-latency/vmcnt/barrier
// legs (m114-style implicit overlap). Depth-2 rotation, vmcnt(4)/phase.
__device__ __forceinline__ void stage2(const char* g, char* l, int kt, int ks) {
    const char* s = g + kt * 128 + ks * 64;
    __builtin_amdgcn_global_load_lds((gas_ptr)(const void*)s,
                                     (las_ptr)(void*)l, 16, 0, 0);
    __builtin_amdgcn_global_load_lds((gas_ptr)(const void*)(s + (size_t)128 * KDIM),
                                     (las_ptr)(void*)(l + 8192), 16, 0, 0);
}

#define BAR   asm volatile("s_barrier" ::: "memory")
#define VM4   asm volatile("s_waitcnt vmcnt(4)" ::: "memory")
#define LGKM0 do { asm volatile("s_waitcnt lgkmcnt(0)" ::: "memory");          \
                   __builtin_amdgcn_sched_barrier(0); } while (0)

#define READ_A8(dst, BASE)                                                     \
    _Pragma("unroll")                                                          \
    for (int ii = 0; ii < 8; ++ii)                                             \
        dst[ii] = *(const v4i*)((BASE) + aoff + ii * 1024)

#define READ_B4(dst, BASE)                                                     \
    _Pragma("unroll")                                                          \
    for (int jj = 0; jj < 4; ++jj)                                             \
        dst[jj] = *(const v4i*)((BASE) + boff + jj * 1024)

#define MMA32(AS, BS)                                                          \
    __builtin_amdgcn_s_setprio(1);                                             \
    _Pragma("unroll")                                                          \
    for (int ii = 0; ii < 8; ++ii)                                             \
        _Pragma("unroll")                                                      \
        for (int jj = 0; jj < 4; ++jj)                                         \
            acc[ii][jj] = __builtin_amdgcn_mfma_i32_16x16x64_i8(               \
                AS[ii], BS[jj], acc[ii][jj], 0, 0, 0);                         \
    __builtin_amdgcn_s_setprio(0)

__global__ __launch_bounds__(512, 4)
void w4a4_gemm2(const char* __restrict__ x8, const char* __restrict__ w8,
                const float* __restrict__ xsc, const float* __restrict__ wsc,
                const float* __restrict__ bias, const float* __restrict__ xr,
                const float* __restrict__ wo, float* __restrict__ out)
{
    // [parity][256 rows x 64B], swizzled: byte c of row r holds global col
    // c ^ (((r>>1)&3)<<4). 64 KiB total -> 2 blocks/CU.
    __shared__ __align__(16) char Ahalf[2][16384];
    __shared__ __align__(16) char Bhalf[2][16384];
    __shared__ float xs_s[256];
    __shared__ float ws_s[256];
    __shared__ float bs_s[256];

    const int tid  = threadIdx.x;
    const int lane = tid & 63;
    const int wid  = tid >> 6;     // 0..7
    const int wm   = wid >> 2;     // M half (0..1)
    const int wn   = wid & 3;      // N quarter (0..3)

    // bijective XCD swizzle: 512 blocks = 8 XCDs x 64
    const int s  = (blockIdx.x & 7) * 64 + (blockIdx.x >> 3);
    const int by = s >> 4;         // 0..31
    const int bxn = s & 15;        // 0..15

    if (tid < 256) {
        xs_s[tid] = xsc[by * 256 + tid];
    } else {
        int n = tid - 256;
        ws_s[n] = wsc[bxn * 256 + n];
        bs_s[n] = bias[bxn * 256 + n];
    }

    // staging geometry: lane covers 16B of row (wid*16 + lane/4), pre-swizzled col
    const int srow = wid * 16 + (lane >> 2);
    const int scol = ((lane & 3) * 16) ^ (((lane >> 3) & 3) << 4);
    const char* gA = x8 + (size_t)(by * 256 + srow) * KDIM + scol;
    const char* gB = w8 + (size_t)(bxn * 256 + srow) * KDIM + scol;
    const int ldsW = wid * 1024;

    // fragment read geometry (swizzle XOR is lane-constant)
    const int lr   = lane & 15;
    const int cef  = ((lane >> 4) << 4) ^ (((lr >> 1) & 3) << 4);
    const int aoff = (wm * 128 + lr) * 64 + cef;
    const int boff = (wn * 64  + lr) * 64 + cef;

    v4i acc[8][4];
#pragma unroll
    for (int i = 0; i < 8; ++i)
#pragma unroll
        for (int j = 0; j < 4; ++j) acc[i][j] = (v4i){0, 0, 0, 0};

    // prologue: half0 -> buf0 (loads 1-4), half1 -> buf1 (loads 5-8)
    stage2(gA, &Ahalf[0][ldsW], 0, 0);
    stage2(gB, &Bhalf[0][ldsW], 0, 0);
    stage2(gA, &Ahalf[1][ldsW], 0, 1);
    stage2(gB, &Bhalf[1][ldsW], 0, 1);
    VM4;                               // certify half0 (leave half1's 4 in flight)
    BAR;

    // Ledger (4 loads/phase/wave): at end of phase h the queue holds
    // {h-1: 4, h: 4}; vmcnt(4) drains h-1's -> certifies half h+1 in
    // buf[(h+1)&1], which phase h+1 reads. Base case: end of phase 0 drains
    // the prologue's half1 loads. WAR: stage into buf[h&1] happens after
    // lgkm(0)+BAR, i.e. after every wave's reads of that buffer completed.
    v4i fa[8], fb[4];
    for (int h = 0; h < NHALF; ++h) {
        const char* Ab = &Ahalf[h & 1][0];
        const char* Bb = &Bhalf[h & 1][0];
        READ_A8(fa, Ab);
        READ_B4(fb, Bb);
        LGKM0;                          // all my reads of buf[h&1] complete
        BAR;                            // ... and everyone else's too
        int hn = h + 2;                 // tail: clamp (dead-but-harmless restage)
        if (hn > NHALF - 1) hn = NHALF - 1;
        stage2(gA, &Ahalf[h & 1][ldsW], hn >> 1, hn & 1);
        stage2(gB, &Bhalf[h & 1][ldsW], hn >> 1, hn & 1);
        MMA32(fa, fb);
        VM4;
        BAR;
    }

    // drain DMAs before overwriting LDS with the f16 outlier tiles
    asm volatile("s_waitcnt vmcnt(0)" ::: "memory");
    BAR;

    // ---- rank-64 outlier staging: f16 [256][64] (128B rows), XOR-swizzled
    // byte ^= ((row&7)<<4); Xh reuses Ahalf (32 KiB), Wh reuses Bhalf.
    char* Xh = (char*)&Ahalf[0][0];
    char* Wh = (char*)&Bhalf[0][0];
    {
        const int rr = tid >> 3;
        const int cb = (tid & 7) * 16;    // byte col within 128B row
#pragma unroll
        for (int p = 0; p < 4; ++p) {
            const int row = p * 64 + rr;
            const int sw = cb ^ ((row & 7) << 4);
            v4f x0 = *(const v4f*)(xr + (size_t)(by * 256 + row) * RDIM + (cb >> 1));
            v4f x1 = *(const v4f*)(xr + (size_t)(by * 256 + row) * RDIM + (cb >> 1) + 4);
            v8h hx = {(_Float16)x0[0], (_Float16)x0[1], (_Float16)x0[2], (_Float16)x0[3],
                      (_Float16)x1[0], (_Float16)x1[1], (_Float16)x1[2], (_Float16)x1[3]};
            *(v8h*)(Xh + (size_t)row * 128 + sw) = hx;
            v4f w0 = *(const v4f*)(wo + (size_t)(bxn * 256 + row) * RDIM + (cb >> 1));
            v4f w1 = *(const v4f*)(wo + (size_t)(bxn * 256 + row) * RDIM + (cb >> 1) + 4);
            v8h hw = {(_Float16)w0[0], (_Float16)w0[1], (_Float16)w0[2], (_Float16)w0[3],
                      (_Float16)w1[0], (_Float16)w1[1], (_Float16)w1[2], (_Float16)w1[3]};
            *(v8h*)(Wh + (size_t)row * 128 + sw) = hw;
        }
    }

    // dequant in place (int acc -> f32 bits), overlaps the LDS staging above
#pragma unroll
    for (int i = 0; i < 8; ++i) {
        const int r0 = wm * 128 + i * 16 + ((lane >> 4) << 2);
        const v4f xs4 = *(const v4f*)&xs_s[r0];
#pragma unroll
        for (int j = 0; j < 4; ++j) {
            const int col = wn * 64 + j * 16 + lr;
            const float sw = ws_s[col];
            const float bz = bs_s[col];
            v4f f;
#pragma unroll
            for (int r = 0; r < 4; ++r)
                f[r] = (float)acc[i][j][r] * xs4[r] * sw + bz;
            acc[i][j] = __builtin_bit_cast(v4i, f);
        }
    }
    __syncthreads();

    // rank-64 outlier, f16 MFMA accumulating into the dequantized f32 frags
#pragma unroll
    for (int ks = 0; ks < 2; ++ks) {
        v8h ah[8], bh[4];
#pragma unroll
        for (int i = 0; i < 8; ++i) {
            const int row = wm * 128 + i * 16 + lr;
            const int c   = (ks * 64 + ((lane >> 4) << 4)) ^ ((row & 7) << 4);
            ah[i] = *(const v8h*)(Xh + (size_t)row * 128 + c);
        }
#pragma unroll
        for (int j = 0; j < 4; ++j) {
            const int row = wn * 64 + j * 16 + lr;
            const int c   = (ks * 64 + ((lane >> 4) << 4)) ^ ((row & 7) << 4);
            bh[j] = *(const v8h*)(Wh + (size_t)row * 128 + c);
        }
#pragma unroll
        for (int i = 0; i < 8; ++i)
#pragma unroll
            for (int j = 0; j < 4; ++j) {
                v4f c = __builtin_bit_cast(v4f, acc[i][j]);
                c = __builtin_amdgcn_mfma_f32_16x16x32_f16(ah[i], bh[j], c, 0, 0, 0);
                acc[i][j] = __builtin_bit_cast(v4i, c);
            }
    }

    const size_t obase = (size_t)(by * 256 + wm * 128 + ((lane >> 4) << 2)) * NDIM
                       + bxn * 256 + wn * 64 + lr;
#pragma unroll
    for (int i = 0; i < 8; ++i)
#pragma unroll
        for (int j = 0; j < 4; ++j) {
            v4f f = __builtin_bit_cast(v4f, acc[i][j]);
#pragma unroll
            for (int r = 0; r < 4; ++r)
                out[obase + (size_t)(i * 16 + r) * NDIM + j * 16] = f[r];
        }
}

// ---------------- fallback: fused single-kernel path (ws too small) --------
__global__ __launch_bounds__(256, 2)
void w4a4_fused(const int* __restrict__ xq, const float* __restrict__ xsc,
                const int* __restrict__ wq, const float* __restrict__ wsc,
                const float* __restrict__ bias, const float* __restrict__ xr,
                const float* __restrict__ wo, float* __restrict__ out)
{
    __shared__ __align__(16) char As[128 * 144];
    __shared__ __align__(16) char Bs[128 * 144];
    __shared__ float xs_s[128];
    __shared__ float ws_s[128];
    __shared__ float bs_s[128];

    const int tid  = threadIdx.x;
    const int lane = tid & 63;
    const int wid  = tid >> 6;
    const int wm   = wid >> 1;
    const int wn   = wid & 1;
    const int bx   = blockIdx.x % (NDIM / 128);
    const int by   = blockIdx.x / (NDIM / 128);

    const int srow   = tid >> 4;
    const int schunk = tid & 15;

    if (tid < 128) {
        xs_s[tid] = xsc[by * 128 + tid];
    } else {
        int n = tid - 128;
        ws_s[n] = wsc[bx * 128 + n];
        bs_s[n] = bias[bx * 128 + n];
    }

    const int* gA = xq + (size_t)(by * 128 + srow) * KW + schunk * 4;
    const int* gB = wq + (size_t)(bx * 128 + srow) * KW + schunk * 4;
    char* lA = As + srow * 144 + schunk * 8;
    char* lB = Bs + srow * 144 + schunk * 8;

    v4i acc[4][4];
#pragma unroll
    for (int i = 0; i < 4; ++i)
#pragma unroll
        for (int j = 0; j < 4; ++j) acc[i][j] = (v4i){0, 0, 0, 0};

    const int lr = lane & 15;
    const int lkb = (lane >> 4) * 16;

    for (int kt = 0; kt < KDIM / 128; ++kt) {
#pragma unroll
        for (int p = 0; p < 8; ++p) {
            v4i w = *(const v4i*)(gA + (size_t)p * 16 * KW + kt * 64);
            int lo8, hi8;
            unpack_w(w, lo8, hi8);
            *(v2i*)(lA + p * 16 * 144) = (v2i){lo8, hi8};
        }
#pragma unroll
        for (int p = 0; p < 8; ++p) {
            v4i w = *(const v4i*)(gB + (size_t)p * 16 * KW + kt * 64);
            int lo8, hi8;
            unpack_w(w, lo8, hi8);
            *(v2i*)(lB + p * 16 * 144) = (v2i){lo8, hi8};
        }
        __syncthreads();
#pragma unroll
        for (int ks = 0; ks < 2; ++ks) {
            v4i av[4], bv[4];
#pragma unroll
            for (int i = 0; i < 4; ++i)
                av[i] = *(const v4i*)(As + (wm * 64 + i * 16 + lr) * 144 + ks * 64 + lkb);
#pragma unroll
            for (int j = 0; j < 4; ++j)
                bv[j] = *(const v4i*)(Bs + (wn * 64 + j * 16 + lr) * 144 + ks * 64 + lkb);
#pragma unroll
            for (int i = 0; i < 4; ++i)
#pragma unroll
                for (int j = 0; j < 4; ++j)
                    acc[i][j] = __builtin_amdgcn_mfma_i32_16x16x64_i8(av[i], bv[j], acc[i][j], 0, 0, 0);
        }
        __syncthreads();
    }

    _Float16* Xh = (_Float16*)As;
    _Float16* Wh = (_Float16*)Bs;
#pragma unroll
    for (int p = 0; p < 8; ++p) {
        int row = p * 16 + srow;
        float4 vx = *(const float4*)(xr + (size_t)(by * 128 + row) * RDIM + schunk * 4);
        *(v4h*)(Xh + row * 72 + schunk * 4) =
            (v4h){(_Float16)vx.x, (_Float16)vx.y, (_Float16)vx.z, (_Float16)vx.w};
        float4 vw = *(const float4*)(wo + (size_t)(bx * 128 + row) * RDIM + schunk * 4);
        *(v4h*)(Wh + row * 72 + schunk * 4) =
            (v4h){(_Float16)vw.x, (_Float16)vw.y, (_Float16)vw.z, (_Float16)vw.w};
    }
    __syncthreads();

    v4f facc[4][4];
#pragma unroll
    for (int i = 0; i < 4; ++i)
#pragma unroll
        for (int j = 0; j < 4; ++j) facc[i][j] = (v4f){0.f, 0.f, 0.f, 0.f};

    const int lkh = (lane >> 4) * 8;
#pragma unroll
    for (int ks = 0; ks < 2; ++ks) {
        v8h ah[4], bh[4];
#pragma unroll
        for (int i = 0; i < 4; ++i)
            ah[i] = *(const v8h*)(Xh + (wm * 64 + i * 16 + lr) * 72 + ks * 32 + lkh);
#pragma unroll
        for (int j = 0; j < 4; ++j)
            bh[j] = *(const v8h*)(Wh + (wn * 64 + j * 16 + lr) * 72 + ks * 32 + lkh);
#pragma unroll
        for (int i = 0; i < 4; ++i)
#pragma unroll
            for (int j = 0; j < 4; ++j)
                facc[i][j] = __builtin_amdgcn_mfma_f32_16x16x32_f16(ah[i], bh[j], facc[i][j], 0, 0, 0);
    }

#pragma unroll
    for (int i = 0; i < 4; ++i) {
        int row0 = wm * 64 + i * 16 + (lane >> 4) * 4;
#pragma unroll
        for (int j = 0; j < 4; ++j) {
            int col = wn * 64 + j * 16 + lr;
            float sw = ws_s[col];
            float bz = bs_s[col];
#pragma unroll
            for (int r = 0; r < 4; ++r) {
                int row = row0 + r;
                float v = (float)acc[i][j][r] * xs_s[row] * sw + bz + facc[i][j][r];
                out[(size_t)(by * 128 + row) * NDIM + (bx * 128 + col)] = v;
            }
        }
    }
}

extern "C" void kernel_launch(void* const* d_in, const int* in_sizes, int n_in,
                              void* d_out, int out_size, void* d_ws, size_t ws_size,
                              hipStream_t stream) {
    const int*   xq   = (const int*)d_in[0];
    const float* xsc  = (const float*)d_in[1];
    const int*   wq   = (const int*)d_in[2];
    const float* wsc  = (const float*)d_in[3];
    const float* bias = (const float*)d_in[4];
    const float* xr   = (const float*)d_in[5];
    const float* wo   = (const float*)d_in[6];
    float* out = (float*)d_out;

    const size_t X8 = (size_t)MDIM * KDIM;
    const size_t W8 = (size_t)NDIM * KDIM;

    if (ws_size >= X8 + W8) {
        char* x8 = (char*)d_ws;
        char* w8 = x8 + X8;
        repack_int4<<<2048, 256, 0, stream>>>(xq, wq, x8, w8);
        w4a4_gemm2<<<(MDIM / 256) * (NDIM / 256), 512, 0, stream>>>(
            x8, w8, xsc, wsc, bias, xr, wo, out);
    } else {
        w4a4_fused<<<(MDIM / 128) * (NDIM / 128), 256, 0, stream>>>(
            xq, xsc, wq, wsc, bias, xr, wo, out);
    }
}

// Round 7
// 182.290 us; speedup vs baseline: 8.8584x; 8.8584x over previous
//
#include <hip/hip_runtime.h>
#include <hip/hip_fp16.h>

typedef int      v4i __attribute__((ext_vector_type(4)));
typedef int      v2i __attribute__((ext_vector_type(2)));
typedef float    v4f __attribute__((ext_vector_type(4)));
typedef _Float16 v8h __attribute__((ext_vector_type(8)));
typedef _Float16 v4h __attribute__((ext_vector_type(4)));

#define MDIM 8192
#define NDIM 4096
#define KDIM 4096
#define RDIM 64
#define KW   (KDIM / 2)
#define NHALF (KDIM / 64)        // 64 K-halves of 64 int8

typedef const __attribute__((address_space(1))) char* gas_ptr;
typedef __attribute__((address_space(3))) char*       las_ptr;

__device__ __forceinline__ void unpack_w(v4i w, int& lo8, int& hi8) {
    unsigned p01 = __builtin_amdgcn_perm((unsigned)w.y, (unsigned)w.x, 0x0C0C0400u);
    unsigned p23 = __builtin_amdgcn_perm((unsigned)w.w, (unsigned)w.z, 0x0C0C0400u);
    unsigned b4  = __builtin_amdgcn_perm(p23, p01, 0x05040100u);
    unsigned lo = b4 & 0x0F0F0F0Fu;
    unsigned hi = (b4 >> 4) & 0x0F0F0F0Fu;
    lo8 = (int)(((lo ^ 0x08080808u) + 0x78787878u) ^ 0x80808080u);
    hi8 = (int)(((hi ^ 0x08080808u) + 0x78787878u) ^ 0x80808080u);
}

// ---------------- kernel 1: repack packed-int32 nibbles -> dense int8 -------
__global__ __launch_bounds__(256)
void repack_int4(const int* __restrict__ xq, const int* __restrict__ wq,
                 char* __restrict__ x8, char* __restrict__ w8)
{
    const size_t XCH = (size_t)MDIM * KW / 4;
    const size_t TCH = XCH + (size_t)NDIM * KW / 4;
    size_t stride = (size_t)gridDim.x * blockDim.x;
    for (size_t i = (size_t)blockIdx.x * blockDim.x + threadIdx.x; i < TCH; i += stride) {
        const int* src;
        char* dst;
        if (i < XCH) { src = xq + i * 4; dst = x8 + i * 8; }
        else { size_t j = i - XCH; src = wq + j * 4; dst = w8 + j * 8; }
        v4i w = *(const v4i*)src;
        int lo8, hi8;
        unpack_w(w, lo8, hi8);
        *(v2i*)dst = (v2i){lo8, hi8};
    }
}

// ---------------- kernel 2: 256x128 int8 GEMM, 2-deep LDS, 2 blocks/CU ------
// Wave tile 64x64 -> acc[4][4]=64 VGPR; total live state ~115 so the kernel
// fits the 128-reg cap of 4 waves/SIMD (r6 lesson: acc[8][4] spilled).
// 50 KiB LDS -> 2 resident blocks/CU whose anti-phased barrier groups hide
// each other's ds-latency/vmcnt/barrier legs under MFMA.
__device__ __forceinline__ void stageA(const char* g, char* l, int hh) {
    const char* s = g + hh * 64;
    __builtin_amdgcn_global_load_lds((gas_ptr)(const void*)s,
                                     (las_ptr)(void*)l, 16, 0, 0);
    __builtin_amdgcn_global_load_lds((gas_ptr)(const void*)(s + (size_t)16 * KDIM),
                                     (las_ptr)(void*)(l + 1024), 16, 0, 0);
}
__device__ __forceinline__ void stageB(const char* g, char* l, int hh) {
    __builtin_amdgcn_global_load_lds((gas_ptr)(const void*)(g + hh * 64),
                                     (las_ptr)(void*)l, 16, 0, 0);
}

#define BAR   asm volatile("s_barrier" ::: "memory")
#define VM3   asm volatile("s_waitcnt vmcnt(3)" ::: "memory")
#define LGKM0 do { asm volatile("s_waitcnt lgkmcnt(0)" ::: "memory");          \
                   __builtin_amdgcn_sched_barrier(0); } while (0)

#define READ_A4(dst, BASE)                                                     \
    _Pragma("unroll")                                                          \
    for (int ii = 0; ii < 4; ++ii)                                             \
        dst[ii] = *(const v4i*)((BASE) + aoff + ii * 1024)

#define READ_B4(dst, BASE)                                                     \
    _Pragma("unroll")                                                          \
    for (int jj = 0; jj < 4; ++jj)                                             \
        dst[jj] = *(const v4i*)((BASE) + boff + jj * 1024)

#define MMA16(AS, BS)                                                          \
    __builtin_amdgcn_s_setprio(1);                                             \
    _Pragma("unroll")                                                          \
    for (int ii = 0; ii < 4; ++ii)                                             \
        _Pragma("unroll")                                                      \
        for (int jj = 0; jj < 4; ++jj)                                         \
            acc[ii][jj] = __builtin_amdgcn_mfma_i32_16x16x64_i8(               \
                AS[ii], BS[jj], acc[ii][jj], 0, 0, 0);                         \
    __builtin_amdgcn_s_setprio(0)

__global__ __launch_bounds__(512, 4)
void w4a4_gemm2(const char* __restrict__ x8, const char* __restrict__ w8,
                const float* __restrict__ xsc, const float* __restrict__ wsc,
                const float* __restrict__ bias, const float* __restrict__ xr,
                const float* __restrict__ wo, float* __restrict__ out)
{
    // [parity][rows x 64B], swizzled: byte c of row r holds global col
    // c ^ (((r>>1)&3)<<4). A: 2x16K, B: 2x8K = 48 KiB + 2 KiB scales.
    __shared__ __align__(16) char Ahalf[2][16384];
    __shared__ __align__(16) char Bhalf[2][8192];
    __shared__ float xs_s[256];
    __shared__ float ws_s[128];
    __shared__ float bs_s[128];

    const int tid  = threadIdx.x;
    const int lane = tid & 63;
    const int wid  = tid >> 6;     // 0..7
    const int wm   = wid >> 1;     // M quarter (0..3)
    const int wn   = wid & 1;      // N half (0..1)

    // bijective XCD swizzle: 1024 blocks = 8 XCDs x 128
    const int s  = (blockIdx.x & 7) * 128 + (blockIdx.x >> 3);
    const int by = s >> 5;         // 0..31
    const int bxn = s & 31;        // 0..31

    if (tid < 256) {
        xs_s[tid] = xsc[by * 256 + tid];
    } else if (tid < 384) {
        int n = tid - 256;
        ws_s[n] = wsc[bxn * 128 + n];
        bs_s[n] = bias[bxn * 128 + n];
    }

    // staging geometry: pre-swizzled source col, linear LDS dest
    const int scol  = ((lane & 3) * 16) ^ (((lane >> 3) & 3) << 4);
    const int srowA = wid * 32 + (lane >> 2);
    const int srowB = wid * 16 + (lane >> 2);
    const char* gA = x8 + (size_t)(by * 256 + srowA) * KDIM + scol;
    const char* gB = w8 + (size_t)(bxn * 128 + srowB) * KDIM + scol;
    const int ldsWA = wid * 2048;
    const int ldsWB = wid * 1024;

    // fragment read geometry (swizzle XOR is lane-constant)
    const int lr   = lane & 15;
    const int cef  = ((lane >> 4) << 4) ^ (((lr >> 1) & 3) << 4);
    const int aoff = (wm * 64 + lr) * 64 + cef;
    const int boff = (wn * 64 + lr) * 64 + cef;

    v4i acc[4][4];
#pragma unroll
    for (int i = 0; i < 4; ++i)
#pragma unroll
        for (int j = 0; j < 4; ++j) acc[i][j] = (v4i){0, 0, 0, 0};

    // prologue: half0 -> buf0 (3 loads/wave), half1 -> buf1 (3 loads/wave)
    stageA(gA, &Ahalf[0][ldsWA], 0);
    stageB(gB, &Bhalf[0][ldsWB], 0);
    stageA(gA, &Ahalf[1][ldsWA], 1);
    stageB(gB, &Bhalf[1][ldsWB], 1);
    VM3;                               // drain half0's 3; half1's 3 in flight
    BAR;

    // Ledger (3 loads/phase/wave): entering phase h, half(h+1)'s 3 loads are
    // in flight. Phase h stages half(h+2) (3 more); VM3 drains half(h+1) ->
    // certified for phase h+1. WAR: stage into buf[h&1] only after
    // lgkm(0)+BAR (all waves' reads of that buffer landed in registers).
    v4i fa[4], fb[4];
    for (int h = 0; h < NHALF; ++h) {
        const char* Ab = &Ahalf[h & 1][0];
        const char* Bb = &Bhalf[h & 1][0];
        READ_A4(fa, Ab);
        READ_B4(fb, Bb);
        LGKM0;                          // my reads of buf[h&1] complete
        BAR;                            // everyone's reads complete
        int hn = h + 2;                 // tail: clamp (dead-but-harmless restage)
        if (hn > NHALF - 1) hn = NHALF - 1;
        stageA(gA, &Ahalf[h & 1][ldsWA], hn);
        stageB(gB, &Bhalf[h & 1][ldsWB], hn);
        __builtin_amdgcn_sched_barrier(0);   // keep stage issue ahead of MFMA
        MMA16(fa, fb);
        VM3;
        BAR;
    }

    // drain DMAs before overwriting LDS with the f16 outlier tiles
    asm volatile("s_waitcnt vmcnt(0)" ::: "memory");
    BAR;

    // ---- rank-64 outlier staging: f16 rows of 128B, XOR-swizzled
    // byte ^= ((row&7)<<4); Xh[256] reuses Ahalf (32K), Wh[128] reuses Bhalf.
    char* Xh = (char*)&Ahalf[0][0];
    char* Wh = (char*)&Bhalf[0][0];
    {
        const int rr = tid >> 3;
        const int cb = (tid & 7) * 16;    // byte col within 128B row
#pragma unroll
        for (int p = 0; p < 4; ++p) {
            const int row = p * 64 + rr;
            const int sw = cb ^ ((row & 7) << 4);
            v4f x0 = *(const v4f*)(xr + (size_t)(by * 256 + row) * RDIM + (cb >> 1));
            v4f x1 = *(const v4f*)(xr + (size_t)(by * 256 + row) * RDIM + (cb >> 1) + 4);
            v8h hx = {(_Float16)x0[0], (_Float16)x0[1], (_Float16)x0[2], (_Float16)x0[3],
                      (_Float16)x1[0], (_Float16)x1[1], (_Float16)x1[2], (_Float16)x1[3]};
            *(v8h*)(Xh + (size_t)row * 128 + sw) = hx;
            if (p < 2) {
                v4f w0 = *(const v4f*)(wo + (size_t)(bxn * 128 + row) * RDIM + (cb >> 1));
                v4f w1 = *(const v4f*)(wo + (size_t)(bxn * 128 + row) * RDIM + (cb >> 1) + 4);
                v8h hw = {(_Float16)w0[0], (_Float16)w0[1], (_Float16)w0[2], (_Float16)w0[3],
                          (_Float16)w1[0], (_Float16)w1[1], (_Float16)w1[2], (_Float16)w1[3]};
                *(v8h*)(Wh + (size_t)row * 128 + sw) = hw;
            }
        }
    }

    // dequant in place (int acc -> f32 bits), overlaps the LDS staging above
#pragma unroll
    for (int i = 0; i < 4; ++i) {
        const int r0 = wm * 64 + i * 16 + ((lane >> 4) << 2);
        const v4f xs4 = *(const v4f*)&xs_s[r0];
#pragma unroll
        for (int j = 0; j < 4; ++j) {
            const int col = wn * 64 + j * 16 + lr;
            const float sw = ws_s[col];
            const float bz = bs_s[col];
            v4f f;
#pragma unroll
            for (int r = 0; r < 4; ++r)
                f[r] = (float)acc[i][j][r] * xs4[r] * sw + bz;
            acc[i][j] = __builtin_bit_cast(v4i, f);
        }
    }
    __syncthreads();

    // rank-64 outlier, f16 MFMA accumulating into the dequantized f32 frags
#pragma unroll
    for (int ks = 0; ks < 2; ++ks) {
        v8h ah[4], bh[4];
#pragma unroll
        for (int i = 0; i < 4; ++i) {
            const int row = wm * 64 + i * 16 + lr;
            const int c   = (ks * 64 + ((lane >> 4) << 4)) ^ ((row & 7) << 4);
            ah[i] = *(const v8h*)(Xh + (size_t)row * 128 + c);
        }
#pragma unroll
        for (int j = 0; j < 4; ++j) {
            const int row = wn * 64 + j * 16 + lr;
            const int c   = (ks * 64 + ((lane >> 4) << 4)) ^ ((row & 7) << 4);
            bh[j] = *(const v8h*)(Wh + (size_t)row * 128 + c);
        }
#pragma unroll
        for (int i = 0; i < 4; ++i)
#pragma unroll
            for (int j = 0; j < 4; ++j) {
                v4f c = __builtin_bit_cast(v4f, acc[i][j]);
                c = __builtin_amdgcn_mfma_f32_16x16x32_f16(ah[i], bh[j], c, 0, 0, 0);
                acc[i][j] = __builtin_bit_cast(v4i, c);
            }
    }

    const size_t obase = (size_t)(by * 256 + wm * 64 + ((lane >> 4) << 2)) * NDIM
                       + bxn * 128 + wn * 64 + lr;
#pragma unroll
    for (int i = 0; i < 4; ++i)
#pragma unroll
        for (int j = 0; j < 4; ++j) {
            v4f f = __builtin_bit_cast(v4f, acc[i][j]);
#pragma unroll
            for (int r = 0; r < 4; ++r)
                out[obase + (size_t)(i * 16 + r) * NDIM + j * 16] = f[r];
        }
}

// ---------------- fallback: fused single-kernel path (ws too small) --------
__global__ __launch_bounds__(256, 2)
void w4a4_fused(const int* __restrict__ xq, const float* __restrict__ xsc,
                const int* __restrict__ wq, const float* __restrict__ wsc,
                const float* __restrict__ bias, const float* __restrict__ xr,
                const float* __restrict__ wo, float* __restrict__ out)
{
    __shared__ __align__(16) char As[128 * 144];
    __shared__ __align__(16) char Bs[128 * 144];
    __shared__ float xs_s[128];
    __shared__ float ws_s[128];
    __shared__ float bs_s[128];

    const int tid  = threadIdx.x;
    const int lane = tid & 63;
    const int wid  = tid >> 6;
    const int wm   = wid >> 1;
    const int wn   = wid & 1;
    const int bx   = blockIdx.x % (NDIM / 128);
    const int by   = blockIdx.x / (NDIM / 128);

    const int srow   = tid >> 4;
    const int schunk = tid & 15;

    if (tid < 128) {
        xs_s[tid] = xsc[by * 128 + tid];
    } else {
        int n = tid - 128;
        ws_s[n] = wsc[bx * 128 + n];
        bs_s[n] = bias[bx * 128 + n];
    }

    const int* gA = xq + (size_t)(by * 128 + srow) * KW + schunk * 4;
    const int* gB = wq + (size_t)(bx * 128 + srow) * KW + schunk * 4;
    char* lA = As + srow * 144 + schunk * 8;
    char* lB = Bs + srow * 144 + schunk * 8;

    v4i acc[4][4];
#pragma unroll
    for (int i = 0; i < 4; ++i)
#pragma unroll
        for (int j = 0; j < 4; ++j) acc[i][j] = (v4i){0, 0, 0, 0};

    const int lr = lane & 15;
    const int lkb = (lane >> 4) * 16;

    for (int kt = 0; kt < KDIM / 128; ++kt) {
#pragma unroll
        for (int p = 0; p < 8; ++p) {
            v4i w = *(const v4i*)(gA + (size_t)p * 16 * KW + kt * 64);
            int lo8, hi8;
            unpack_w(w, lo8, hi8);
            *(v2i*)(lA + p * 16 * 144) = (v2i){lo8, hi8};
        }
#pragma unroll
        for (int p = 0; p < 8; ++p) {
            v4i w = *(const v4i*)(gB + (size_t)p * 16 * KW + kt * 64);
            int lo8, hi8;
            unpack_w(w, lo8, hi8);
            *(v2i*)(lB + p * 16 * 144) = (v2i){lo8, hi8};
        }
        __syncthreads();
#pragma unroll
        for (int ks = 0; ks < 2; ++ks) {
            v4i av[4], bv[4];
#pragma unroll
            for (int i = 0; i < 4; ++i)
                av[i] = *(const v4i*)(As + (wm * 64 + i * 16 + lr) * 144 + ks * 64 + lkb);
#pragma unroll
            for (int j = 0; j < 4; ++j)
                bv[j] = *(const v4i*)(Bs + (wn * 64 + j * 16 + lr) * 144 + ks * 64 + lkb);
#pragma unroll
            for (int i = 0; i < 4; ++i)
#pragma unroll
                for (int j = 0; j < 4; ++j)
                    acc[i][j] = __builtin_amdgcn_mfma_i32_16x16x64_i8(av[i], bv[j], acc[i][j], 0, 0, 0);
        }
        __syncthreads();
    }

    _Float16* Xh = (_Float16*)As;
    _Float16* Wh = (_Float16*)Bs;
#pragma unroll
    for (int p = 0; p < 8; ++p) {
        int row = p * 16 + srow;
        float4 vx = *(const float4*)(xr + (size_t)(by * 128 + row) * RDIM + schunk * 4);
        *(v4h*)(Xh + row * 72 + schunk * 4) =
            (v4h){(_Float16)vx.x, (_Float16)vx.y, (_Float16)vx.z, (_Float16)vx.w};
        float4 vw = *(const float4*)(wo + (size_t)(bx * 128 + row) * RDIM + schunk * 4);
        *(v4h*)(Wh + row * 72 + schunk * 4) =
            (v4h){(_Float16)vw.x, (_Float16)vw.y, (_Float16)vw.z, (_Float16)vw.w};
    }
    __syncthreads();

    v4f facc[4][4];
#pragma unroll
    for (int i = 0; i < 4; ++i)
#pragma unroll
        for (int j = 0; j < 4; ++j) facc[i][j] = (v4f){0.f, 0.f, 0.f, 0.f};

    const int lkh = (lane >> 4) * 8;
#pragma unroll
    for (int ks = 0; ks < 2; ++ks) {
        v8h ah[4], bh[4];
#pragma unroll
        for (int i = 0; i < 4; ++i)
            ah[i] = *(const v8h*)(Xh + (wm * 64 + i * 16 + lr) * 72 + ks * 32 + lkh);
#pragma unroll
        for (int j = 0; j < 4; ++j)
            bh[j] = *(const v8h*)(Wh + (wn * 64 + j * 16 + lr) * 72 + ks * 32 + lkh);
#pragma unroll
        for (int i = 0; i < 4; ++i)
#pragma unroll
            for (int j = 0; j < 4; ++j)
                facc[i][j] = __builtin_amdgcn_mfma_f32_16x16x32_f16(ah[i], bh[j], facc[i][j], 0, 0, 0);
    }

#pragma unroll
    for (int i = 0; i < 4; ++i) {
        int row0 = wm * 64 + i * 16 + (lane >> 4) * 4;
#pragma unroll
        for (int j = 0; j < 4; ++j) {
            int col = wn * 64 + j * 16 + lr;
            float sw = ws_s[col];
            float bz = bs_s[col];
#pragma unroll
            for (int r = 0; r < 4; ++r) {
                int row = row0 + r;
                float v = (float)acc[i][j][r] * xs_s[row] * sw + bz + facc[i][j][r];
                out[(size_t)(by * 128 + row) * NDIM + (bx * 128 + col)] = v;
            }
        }
    }
}

extern "C" void kernel_launch(void* const* d_in, const int* in_sizes, int n_in,
                              void* d_out, int out_size, void* d_ws, size_t ws_size,
                              hipStream_t stream) {
    const int*   xq   = (const int*)d_in[0];
    const float* xsc  = (const float*)d_in[1];
    const int*   wq   = (const int*)d_in[2];
    const float* wsc  = (const float*)d_in[3];
    const float* bias = (const float*)d_in[4];
    const float* xr   = (const float*)d_in[5];
    const float* wo   = (const float*)d_in[6];
    float* out = (float*)d_out;

    const size_t X8 = (size_t)MDIM * KDIM;
    const size_t W8 = (size_t)NDIM * KDIM;

    if (ws_size >= X8 + W8) {
        char* x8 = (char*)d_ws;
        char* w8 = x8 + X8;
        repack_int4<<<2048, 256, 0, stream>>>(xq, wq, x8, w8);
        w4a4_gemm2<<<(MDIM / 256) * (NDIM / 128), 512, 0, stream>>>(
            x8, w8, xsc, wsc, bias, xr, wo, out);
    } else {
        w4a4_fused<<<(MDIM / 128) * (NDIM / 128), 256, 0, stream>>>(
            xq, xsc, wq, wsc, bias, xr, wo, out);
    }
}